// Round 14
// baseline (864.105 us; speedup 1.0000x reference)
//
#include <hip/hip_runtime.h>
#include <math.h>

#define SS   0.1f
#define THRC 0.01f   // LMBD * MU

typedef __attribute__((ext_vector_type(8))) short s16x8;
typedef __attribute__((ext_vector_type(4))) float f32x4;

__device__ __forceinline__ float b2f(unsigned short u){
  union{unsigned int i; float f;} v; v.i = ((unsigned int)u)<<16; return v.f;
}
__device__ __forceinline__ unsigned short f2b(float f){
  union{float f; unsigned int i;} v; v.f = f;
  return (unsigned short)((v.i + 0x7fffu + ((v.i>>16)&1u))>>16);  // RNE
}
__device__ __forceinline__ s16x8 as_s16x8(uint4 u){
  union{uint4 a; s16x8 b;} c; c.a = u; return c.b;
}
// 8 quads/row; XOR swizzle -> <=2-way conflicts on ds_read. DMA writes LDS linearly
// with SOURCE quads pre-swizzled (same involution both sides).
__device__ __forceinline__ int swz8(int row, int q){ return (row<<3) | (q ^ (row&7)); }

// async global->LDS, 16B/lane; dest = wave-uniform base + lane*16, source per-lane.
__device__ __forceinline__ void gld16(const void* g, void* l){
  __builtin_amdgcn_global_load_lds(
      (const __attribute__((address_space(1))) unsigned int*)g,
      (__attribute__((address_space(3))) unsigned int*)l, 16, 0, 0);
}

enum { EPI_FIRST=0, EPI_UPDATE=1, EPI_PARTIAL=2, EPI_TPART=3, EPI_GRAM=4 };

struct EpiM {
  unsigned short* C;            // dest (c / partial)
  const unsigned short* Y;      // y for UPDATE/GRAM
  const unsigned short* Cprev;  // c_{t-1} for fused y-update
  unsigned short* Yout;         // fused y_{t+1} output (optional)
  const unsigned short* img;    // b = ss*conv(x) for GRAM
  const unsigned short* zp;     // 16B zeros page for OOB DMA lanes
  float coef;
  int S_MN, Kc, lgS;            // split-K geometry
};

// -------- A-tile loaders: return 16B-aligned address of 8 contiguous bf16 --------
struct LA_ident {
  const unsigned short* A; int K;
  __device__ void setz(int){}
  __device__ __forceinline__ const unsigned short* addr(int m, int k8) const {
    return A + (size_t)m*K + ((size_t)k8<<3);
  }
};
struct LA_nhwc {   // im2col, NHWC bf16, stride2 pad1 k4; k = (kh*4+kw)*C + i
  const unsigned short* img; const unsigned short* zp; int lH, lW, lC;
  __device__ void setz(int){}
  __device__ __forceinline__ const unsigned short* addr(int m, int k8) const {
    int lWo = lW-1, lHo = lH-1;
    int wo = m & ((1<<lWo)-1); int t = m>>lWo; int ho = t & ((1<<lHo)-1); int b = t>>lHo;
    int k = k8<<3; int kk = k>>lC; int i = k & ((1<<lC)-1);
    int kw = kk&3, kh = kk>>2;
    int h = 2*ho + kh - 1, w = 2*wo + kw - 1;
    if ((unsigned)h >= (1u<<lH) || (unsigned)w >= (1u<<lW)) return zp;
    return img + (((((((size_t)b<<lH)|h)<<lW)|w))<<lC) + i;
  }
};
struct LA_yg {     // parity-class tconv gather of code y; k = (th*2+tw)*O + o
  const unsigned short* y; const unsigned short* zp; int lHo, lWo, lO, ph, pw;
  __device__ void setz(int z){ ph = z>>1; pw = z&1; }
  __device__ __forceinline__ const unsigned short* addr(int m, int k8) const {
    int l = m & ((1<<lWo)-1); int t = m>>lWo; int j = t & ((1<<lHo)-1); int b = t>>lHo;
    int k = k8<<3; int tt = k>>lO; int o = k & ((1<<lO)-1);
    int th = tt>>1, tw = tt&1;
    int ho = ph ? (j+1-th) : (j-th);
    int wo = pw ? (l+1-tw) : (l-tw);
    if ((unsigned)ho >= (1u<<lHo) || (unsigned)wo >= (1u<<lWo)) return zp;
    return y + (((((((size_t)b<<lHo)|ho)<<lWo)|wo))<<lO) + o;
  }
};
struct LA_padb {   // layer-1 im2col from padded bf16 NHWC4 [256][34][34][4]; k=(kh*4+kw)*4+c
  const unsigned short* img;
  __device__ void setz(int){}
  __device__ __forceinline__ const unsigned short* addr(int m, int k8) const {
    int wo = m&15, t = m>>4, ho = t&15, b = t>>4;
    int kh = k8>>1, kw0 = (k8&1)<<1;
    int h = 2*ho + kh, w = 2*wo + kw0;          // w even -> 16B aligned
    return img + (((size_t)b*34 + h)*34 + w)*4;
  }
};

// ---- MFMA GEMM: 128x128 tile, BK=64, 8 waves (2x4), wave=64x32, SINGLE-buffer ----
// m97 design point: 32KB LDS -> 4 blocks/CU co-resident (512thr x 4 = 2048 = CU cap).
// Inter-block wave overlap hides the per-step drain. Host splits K so hot dispatches
// have ~1024 blocks. Split-K reduction stays in SEPARATE kernels: the fused
// last-block variant (R10/R11) required per-block device-scope fences -> L2
// writeback/invalidate storms (MfmaUtil 1.5%). Kernel-boundary fence is once, not 1024x.
template<class AL, int EPI>
__global__ __launch_bounds__(512)
void mgemm_k(AL al, const unsigned short* __restrict__ Bw, int M, int N, int K, EpiM ep)
{
  __shared__ uint4 As[1024];   // 16KB
  __shared__ uint4 Bs[1024];   // 16KB
  const int tid = threadIdx.x;
  const int bm = blockIdx.y<<7, bn = blockIdx.x<<7;
  const int z = blockIdx.z;
  int kb = 0, ke = K;
  const unsigned short* Bp = Bw;
  if (EPI == EPI_PARTIAL){ kb = z*ep.Kc; ke = kb + ep.Kc; }
  if (EPI == EPI_TPART){
    int cls = z >> ep.lgS, kz = z & ((1<<ep.lgS)-1);
    Bp = Bw + (size_t)cls*(size_t)N*K; al.setz(cls);
    kb = kz*ep.Kc; ke = kb + ep.Kc;
  }

  f32x4 acc[4][2];
  #pragma unroll
  for (int i=0;i<4;++i)
    #pragma unroll
    for (int j=0;j<2;++j){ acc[i][j][0]=0.f; acc[i][j][1]=0.f; acc[i][j][2]=0.f; acc[i][j][3]=0.f; }

  const int lane = tid & 63, wid = tid >> 6;
  const int wm = (wid>>2)<<6, wn = (wid&3)<<5;     // wave tile 64x32
  const int fr = lane & 15, fq = lane >> 4;

  // DMA slot mapping: slot s -> row s>>3; lds-quad j=s&7 holds global quad
  // q = j ^ (row&7) (self-inverse; matches swz8 on the read side).
  auto issueA = [&](int k0){
    int k8 = k0>>3;
    #pragma unroll
    for (int i=0;i<2;++i){
      int s  = (wid<<7) + (i<<6) + lane;
      int sr = s>>3, q = (s&7) ^ (sr&7);
      gld16(al.addr(bm+sr, k8+q), (void*)&As[(wid<<7) + (i<<6)]);
    }
  };
  auto issueB = [&](int k0){
    int k8 = k0>>3;
    #pragma unroll
    for (int i=0;i<2;++i){
      int s  = (wid<<7) + (i<<6) + lane;
      int sr = s>>3, q = (s&7) ^ (sr&7);
      int gn = bn + sr;
      const unsigned short* src = (gn < N) ? Bp + (size_t)gn*K + ((size_t)(k8+q)<<3) : ep.zp;
      gld16(src, (void*)&Bs[(wid<<7) + (i<<6)]);
    }
  };

  for (int k0 = kb; k0 < ke; k0 += 64){
    issueA(k0); issueB(k0);
    asm volatile("s_waitcnt vmcnt(0)" ::: "memory");  // my DMAs landed
    __builtin_amdgcn_s_barrier();                     // everyone's landed
    __builtin_amdgcn_sched_barrier(0);
    #pragma unroll
    for (int half=0; half<2; ++half){
      const int qb = (half<<2) | fq;
      s16x8 af[4], bf[2];
      #pragma unroll
      for (int mi=0;mi<4;++mi) af[mi] = as_s16x8(As[swz8(wm + mi*16 + fr, qb)]);
      #pragma unroll
      for (int ni=0;ni<2;++ni) bf[ni] = as_s16x8(Bs[swz8(wn + ni*16 + fr, qb)]);
      #pragma unroll
      for (int mi=0;mi<4;++mi)
        #pragma unroll
        for (int ni=0;ni<2;++ni)
          acc[mi][ni] = __builtin_amdgcn_mfma_f32_16x16x32_bf16(af[mi], bf[ni], acc[mi][ni], 0,0,0);
    }
    if (k0 + 64 < ke){
      __builtin_amdgcn_s_barrier();                   // reads retired -> safe overwrite
      __builtin_amdgcn_sched_barrier(0);
    }
  }

  // epilogue: D lane map col=lane&15, row=(lane>>4)*4+reg
  #pragma unroll
  for (int mi=0;mi<4;++mi){
    #pragma unroll
    for (int ni=0;ni<2;++ni){
      int n = bn + wn + ni*16 + fr;
      if (n >= N) continue;
      int mb = bm + wm + mi*16 + (fq<<2);
      #pragma unroll
      for (int r=0;r<4;++r){
        int m = mb + r;
        float a = acc[mi][ni][r];
        if (EPI == EPI_FIRST){
          float v = SS*a - THRC; v = v>0.f ? v : 0.f;
          ep.C[(size_t)m*N + n] = f2b(v);
        } else if (EPI == EPI_UPDATE){
          size_t idx = (size_t)m*N + n;
          float v = b2f(ep.Y[idx]) + SS*a - THRC; v = v>0.f ? v : 0.f;
          ep.C[idx] = f2b(v);
          if (ep.Yout) ep.Yout[idx] = f2b(v + ep.coef*(v - b2f(ep.Cprev[idx])));
        } else if (EPI == EPI_PARTIAL || EPI == EPI_TPART){
          ep.C[(size_t)z*ep.S_MN + (size_t)m*N + n] = f2b(a);
        } else { // EPI_GRAM: c = shrink(y + b - ss*(y*G)), fused y-update
          size_t idx = (size_t)m*N + n;
          float v = b2f(ep.Y[idx]) + b2f(ep.img[idx]) - SS*a - THRC; v = v>0.f ? v : 0.f;
          ep.C[idx] = f2b(v);
          if (ep.Yout) ep.Yout[idx] = f2b(v + ep.coef*(v - b2f(ep.Cprev[idx])));
        }
      }
    }
  }
}

// ---------------- weight normalization ----------------
__global__ __launch_bounds__(64)
void wnorm1_k(const float* __restrict__ w, unsigned short* __restrict__ wf1,
              unsigned short* __restrict__ wcolT)
{
  int o = blockIdx.x, tid = threadIdx.x;
  __shared__ float red[64];
  float v = (tid < 48) ? w[(size_t)o*48 + tid] : 0.f;  // tid = c*16 + t
  red[tid] = v*v; __syncthreads();
  for (int d=32; d>0; d>>=1){ if (tid<d) red[tid] += red[tid+d]; __syncthreads(); }
  float nv = v * rsqrtf(red[0]);
  if (tid < 48){
    int c = tid>>4, t = tid&15;
    wf1[(size_t)o*64 + t*4 + c] = f2b(nv);
    wcolT[(size_t)(t*4+c)*128 + o] = f2b(nv);
  } else {
    int t = tid - 48;
    wf1[(size_t)o*64 + t*4 + 3] = 0;
    wcolT[(size_t)(t*4+3)*128 + o] = 0;
  }
}
__global__ __launch_bounds__(256)
void wnormX_k(const float* __restrict__ w, int Cin, int O,
              unsigned short* __restrict__ wT, unsigned short* __restrict__ wclsT,
              unsigned short* __restrict__ wEO)
{
  int o = blockIdx.x, tid = threadIdx.x; int E = Cin*16;
  __shared__ float red[256];
  float s = 0.f;
  for (int e = tid; e < E; e += 256){ float v = w[(size_t)o*E + e]; s += v*v; }
  red[tid] = s; __syncthreads();
  for (int d=128; d>0; d>>=1){ if (tid<d) red[tid] += red[tid+d]; __syncthreads(); }
  float scale = rsqrtf(red[0]);
  for (int e = tid; e < E; e += 256){
    float v = w[(size_t)o*E + e] * scale;
    int i = e>>4, t = e&15, kh = t>>2, kw = t&3;
    int ee = t*Cin + i;
    if (wT)  wT[(size_t)o*E + ee] = f2b(v);
    if (wEO) wEO[(size_t)ee*O + o] = f2b(v);
    if (wclsT){
      int ph = (kh&1)^1, pw = (kw&1)^1, cls = ph*2+pw;
      int tt = (kh>>1)*2 + (kw>>1);
      wclsT[(((size_t)cls*Cin + i)*4 + tt)*O + o] = f2b(v);
    }
  }
}

// ---------------- small kernels ----------------
// split-K reduce + shrink (+ fused y-update) (+ optional fused BN-stats), vec x8.
// bns!=nullptr: accumulate per-channel sum/sumsq of the shrunk values into bns[0..O)
// and bns[O..2O) via LDS staging + per-block global atomics (O power of 2).
__global__ void splitk_shrink_k(const unsigned short* __restrict__ part,
                                const unsigned short* __restrict__ Y,
                                unsigned short* __restrict__ C,
                                unsigned short* __restrict__ Yout,
                                const unsigned short* __restrict__ Cprev,
                                float coef, int MN, int S,
                                float* __restrict__ bns, int O)
{
  __shared__ float ls[1024];   // up to 512 ch x {sum, sumsq}
  if (bns){
    for (int i = threadIdx.x; i < 2*O; i += blockDim.x) ls[i] = 0.f;
    __syncthreads();
  }
  int total8 = MN>>3;
  for (int i8 = blockIdx.x*blockDim.x + threadIdx.x; i8 < total8; i8 += gridDim.x*blockDim.x){
    size_t off = (size_t)i8<<3;
    float s[8];
    #pragma unroll
    for (int j=0;j<8;++j) s[j]=0.f;
    for (int zz = 0; zz < S; ++zz){
      uint4 pv = *(const uint4*)(part + (size_t)zz*MN + off);
      const unsigned short* pe = (const unsigned short*)&pv;
      #pragma unroll
      for (int j=0;j<8;++j) s[j] += b2f(pe[j]);
    }
    uint4 yv = make_uint4(0,0,0,0), cp = make_uint4(0,0,0,0);
    if (Y)    yv = *(const uint4*)(Y + off);
    if (Yout) cp = *(const uint4*)(Cprev + off);
    const unsigned short* ye = (const unsigned short*)&yv;
    const unsigned short* ce = (const unsigned short*)&cp;
    unsigned short co[8], yo[8];
    int cb = bns ? (int)(off & (unsigned)(O-1)) : 0;
    #pragma unroll
    for (int j=0;j<8;++j){
      float v = (Y ? b2f(ye[j]) : 0.f) + SS*s[j] - THRC; v = v>0.f ? v : 0.f;
      co[j] = f2b(v);
      if (Yout) yo[j] = f2b(v + coef*(v - b2f(ce[j])));
      if (bns){ atomicAdd(&ls[cb+j], v); atomicAdd(&ls[O+cb+j], v*v); }
    }
    *(uint4*)(C + off) = *(const uint4*)co;
    if (Yout) *(uint4*)(Yout + off) = *(const uint4*)yo;
  }
  if (bns){
    __syncthreads();
    for (int i = threadIdx.x; i < 2*O; i += blockDim.x)
      if (ls[i] != 0.f) atomicAdd(&bns[i], ls[i]);
  }
}

// split-K combine: mode 0 -> out1 = f2b(sum); mode 1 -> out1 = f2b(SS*sum),
// out2 = f2b(relu(SS*sum - THRC))   (L4: b and c0 in one pass)
__global__ void combine_k(const unsigned short* __restrict__ part,
                          unsigned short* __restrict__ out1,
                          unsigned short* __restrict__ out2,
                          int MN, int S, int mode)
{
  int total8 = MN>>3;
  for (int i8 = blockIdx.x*blockDim.x + threadIdx.x; i8 < total8; i8 += gridDim.x*blockDim.x){
    size_t off = (size_t)i8<<3;
    float s[8];
    #pragma unroll
    for (int j=0;j<8;++j) s[j]=0.f;
    for (int zz = 0; zz < S; ++zz){
      uint4 pv = *(const uint4*)(part + (size_t)zz*MN + off);
      const unsigned short* pe = (const unsigned short*)&pv;
      #pragma unroll
      for (int j=0;j<8;++j) s[j] += b2f(pe[j]);
    }
    unsigned short o1[8], o2[8];
    #pragma unroll
    for (int j=0;j<8;++j){
      if (mode == 0){ o1[j] = f2b(s[j]); }
      else {
        float bsc = SS*s[j];
        o1[j] = f2b(bsc);
        float v = bsc - THRC; v = v>0.f ? v : 0.f;
        o2[j] = f2b(v);
      }
    }
    *(uint4*)(out1 + off) = *(const uint4*)o1;
    if (mode == 1) *(uint4*)(out2 + off) = *(const uint4*)o2;
  }
}

// tconv split-K combine: r = img - sum_kz partial[cls(idx)*S+kz], vectorized x8 over c
__global__ void tcomb_k(const unsigned short* __restrict__ part,
                        const unsigned short* __restrict__ img,
                        unsigned short* __restrict__ outp,
                        int lH, int lW, int lC, int S, int MN, int total8)
{
  for (int i8 = blockIdx.x*blockDim.x + threadIdx.x; i8 < total8; i8 += gridDim.x*blockDim.x){
    size_t idx = (size_t)i8<<3;
    int c = (int)(idx & ((1u<<lC)-1));
    int w = (int)(idx>>lC) & ((1<<lW)-1);
    int h = (int)(idx>>(lC+lW)) & ((1<<lH)-1);
    int b = (int)(idx>>(lC+lW+lH));
    int j = h>>1, l = w>>1, cls = ((h&1)<<1)|(w&1);
    int m = (((b<<(lH-1))|j)<<(lW-1))|l;
    int N = 1<<lC;
    const unsigned short* pb = part + ((size_t)cls*S)*MN + (size_t)m*N + c;
    float s[8];
    #pragma unroll
    for (int q=0;q<8;++q) s[q]=0.f;
    for (int kz=0; kz<S; ++kz){
      uint4 pv = *(const uint4*)(pb + (size_t)kz*MN);
      const unsigned short* pe = (const unsigned short*)&pv;
      #pragma unroll
      for (int q=0;q<8;++q) s[q] += b2f(pe[q]);
    }
    uint4 iv = *(const uint4*)(img + idx);
    const unsigned short* ie = (const unsigned short*)&iv;
    unsigned short ro[8];
    #pragma unroll
    for (int q=0;q<8;++q) ro[q] = f2b(b2f(ie[q]) - s[q]);
    *(uint4*)(outp + idx) = *(const uint4*)ro;
  }
}

__global__ void pad_x_k(const float* __restrict__ x, unsigned short* __restrict__ xpb){
  int idx = blockIdx.x*256 + threadIdx.x;
  if (idx >= 262144) return;
  int w = idx&31, t = idx>>5, h = t&31, b = t>>5;
  size_t src = (size_t)b*3072 + h*32 + w;
  unsigned short* d = xpb + (((size_t)b*34 + h+1)*34 + w+1)*4;
  d[0] = f2b(x[src]); d[1] = f2b(x[src+1024]); d[2] = f2b(x[src+2048]); d[3] = 0;
}

__global__ void l1_resid_k(const unsigned short* __restrict__ Col,
                           const float* __restrict__ x, unsigned short* __restrict__ r1pb)
{
  int idx = blockIdx.x*256 + threadIdx.x;
  if (idx >= 262144) return;
  int w = idx&31, t = idx>>5, h = t&31, b = t>>5;
  float a0=0.f, a1=0.f, a2=0.f;
  #pragma unroll
  for (int kh=0; kh<4; ++kh){
    int hh = h+1-kh; if (hh & 1) continue; int ho = hh>>1; if ((unsigned)ho >= 16u) continue;
    #pragma unroll
    for (int kw=0; kw<4; ++kw){
      int ww = w+1-kw; if (ww & 1) continue; int wo = ww>>1; if ((unsigned)wo >= 16u) continue;
      int m = (b*16+ho)*16+wo;
      // 4 contiguous shorts (8B aligned): channels 0..2 + zero pad channel
      uint2 pv = *(const uint2*)(Col + (size_t)m*64 + (kh*4+kw)*4);
      const unsigned short* pe = (const unsigned short*)&pv;
      a0 += b2f(pe[0]); a1 += b2f(pe[1]); a2 += b2f(pe[2]);
    }
  }
  size_t src = (size_t)b*3072 + h*32 + w;
  unsigned short* d = r1pb + (((size_t)b*34 + h+1)*34 + w+1)*4;
  d[0] = f2b(x[src] - a0); d[1] = f2b(x[src+1024] - a1); d[2] = f2b(x[src+2048] - a2); d[3] = 0;
}

__global__ void bn_apply_k(const unsigned short* __restrict__ d, const float* __restrict__ sums,
                           const float* __restrict__ g, const float* __restrict__ bta,
                           unsigned short* __restrict__ outp, int rows, int O, float inv_cnt){
  int total = rows*O;
  for (int i = blockIdx.x*blockDim.x + threadIdx.x; i < total; i += gridDim.x*blockDim.x){
    int c = i % O;
    float mean = sums[c]*inv_cnt;
    float var  = sums[O+c]*inv_cnt - mean*mean;
    float v = g[c]*(b2f(d[i])-mean)*rsqrtf(var + 1e-5f) + bta[c];
    outp[i] = f2b(v >= 0.f ? v : 0.2f*v);
  }
}

__global__ __launch_bounds__(256)
void norm_rows_k(const unsigned short* __restrict__ h, float* __restrict__ out){
  int row = blockIdx.x, tid = threadIdx.x;
  __shared__ float red[256];
  float v = b2f(h[(size_t)row*256 + tid]);
  red[tid] = v*v; __syncthreads();
  for (int d=128; d>0; d>>=1){ if (tid<d) red[tid] += red[tid+d]; __syncthreads(); }
  float nrm = sqrtf(red[0]); nrm = nrm > 1e-12f ? nrm : 1e-12f;
  out[(size_t)row*256 + tid] = v / nrm;
}

// ---------------- host ----------------
extern "C" void kernel_launch(void* const* d_in, const int* in_sizes, int n_in,
                              void* d_out, int out_size, void* d_ws, size_t ws_size,
                              hipStream_t stream)
{
  const float* x  = (const float*)d_in[0];
  const float* w1 = (const float*)d_in[1];
  const float* w2 = (const float*)d_in[2];
  const float* w3 = (const float*)d_in[3];
  const float* w4 = (const float*)d_in[4];
  const float* g2 = (const float*)d_in[5];
  const float* b2 = (const float*)d_in[6];
  const float* g3 = (const float*)d_in[7];
  const float* b3 = (const float*)d_in[8];
  float* out = (float*)d_out;

  char* p = (char*)d_ws;
  auto ah = [&](size_t n){ unsigned short* r = (unsigned short*)p; p += n*2; return r; };
  auto af = [&](size_t n){ float* r = (float*)p; p += n*4; return r; };

  unsigned short* wf1    = ah(128*64);
  unsigned short* wcol1T = ah(64*128);
  unsigned short* wT2    = ah((size_t)256*2048);
  unsigned short* wcls2  = ah((size_t)4*128*1024);
  unsigned short* wT3    = ah((size_t)512*4096);
  unsigned short* wcls3  = ah((size_t)4*256*2048);
  unsigned short* wT4    = ah((size_t)256*8192);
  unsigned short* Gm     = ah((size_t)256*256);   // L4 Gram W*W^T (bf16)
  unsigned short* bb     = ah((size_t)65536);     // L4 b = ss*conv(h3)
  unsigned short* h1     = ah((size_t)8388608);
  unsigned short* h2     = ah((size_t)4194304);
  unsigned short* h3     = ah((size_t)2097152);
  unsigned short* cA     = ah((size_t)8388608);
  unsigned short* cB     = ah((size_t)8388608);
  unsigned short* yA     = ah((size_t)8388608);
  unsigned short* yB     = ah((size_t)8388608);
  unsigned short* rH     = ah((size_t)8388608);
  // union scratch (33.5MB): L1 {Col 8.39 + xpb 2.37 + r1pb 2.37}
  //                         L2/L3 splits {8x/16x partial slices} / L4 {4.2MB}
  char* regionA = p; p += 33554432;
  unsigned short* Col    = (unsigned short*)regionA;                       // 65536 x 64 bf16
  unsigned short* xpb    = (unsigned short*)(regionA + 8388608);           // 256*34*34*4 bf16
  unsigned short* r1pb   = (unsigned short*)(regionA + 8388608 + 2367488);
  unsigned short* partB  = (unsigned short*)regionA;                       // split-K partials
  float* bnsum = af(1024);
  unsigned short* zp16 = ah(128);   // zeros page for OOB DMA lanes (256B)

  double tk = 1.0; float coef[4] = {0.f,0.f,0.f,0.f};
  for (int t = 1; t < 4; ++t){
    double tkp = tk; tk = (1.0 + sqrt(1.0 + 4.0*tkp*tkp))*0.5;
    coef[t] = (float)((tkp - 1.0)/tk);
  }

  hipMemsetAsync(zp16, 0, 256, stream);
  hipMemsetAsync(xpb,  0, 2367488, stream);
  hipMemsetAsync(r1pb, 0, 2367488, stream);
  pad_x_k<<<1024,256,0,stream>>>(x, xpb);
  wnorm1_k<<<128, 64, 0, stream>>>(w1, wf1, wcol1T);
  wnormX_k<<<256,256,0,stream>>>(w2, 128, 256, wT2, wcls2, nullptr);
  wnormX_k<<<512,256,0,stream>>>(w3, 256, 512, wT3, wcls3, nullptr);
  wnormX_k<<<256,256,0,stream>>>(w4, 512, 256, wT4, nullptr, nullptr);

  // ---------- Layer 1: padded bf16 NHWC4 -> code (65536,128), K=64 ----------
  auto l1_fwd = [&](const unsigned short* src, const unsigned short* Y, const unsigned short* Cp,
                    unsigned short* Cout, unsigned short* Yout, float cf){
    LA_padb al{src};
    EpiM ep{}; ep.C=Cout; ep.Y=Y; ep.Cprev=Cp; ep.Yout=Yout; ep.coef=cf; ep.zp=zp16;
    dim3 g(1, 512, 1);
    if (Y) mgemm_k<LA_padb,EPI_UPDATE><<<g,512,0,stream>>>(al, wf1, 65536,128,64, ep);
    else   mgemm_k<LA_padb,EPI_FIRST ><<<g,512,0,stream>>>(al, wf1, 65536,128,64, ep);
  };
  auto l1_tconv = [&](const unsigned short* y){
    LA_ident al{y, 128};
    EpiM ep{}; ep.C=Col; ep.S_MN=0; ep.Kc=128; ep.zp=zp16;
    mgemm_k<LA_ident,EPI_PARTIAL><<<dim3(1,512,1),512,0,stream>>>(al, wcol1T, 65536,64,128, ep);
    l1_resid_k<<<1024,256,0,stream>>>(Col, x, r1pb);
  };
  l1_fwd(xpb,  nullptr, nullptr, cA, nullptr, 0.f);    // c0 (=y1)
  l1_tconv(cA);
  l1_fwd(r1pb, cA, cA, cB, yA, coef[2]);               // c1, y2
  l1_tconv(yA);
  l1_fwd(r1pb, yA, cB, cA, yB, coef[3]);               // c2, y3
  l1_tconv(yB);
  l1_fwd(r1pb, yB, nullptr, h1, nullptr, 0.f);         // c3 -> h1

  // ---------- Layer 2: (16384,256), K=2048: split-K S=4 -> 1024 blocks ----------
  auto l2_fwd = [&](const unsigned short* src, const unsigned short* Y, const unsigned short* Cp,
                    unsigned short* Cout, unsigned short* Yout, float cf, float* bns){
    LA_nhwc al{src, zp16, 4,4,7};
    EpiM ep{}; ep.C=partB; ep.S_MN=16384*256; ep.Kc=512; ep.zp=zp16;
    mgemm_k<LA_nhwc,EPI_PARTIAL><<<dim3(2,128,4),512,0,stream>>>(al, wT2, 16384,256,2048, ep);
    splitk_shrink_k<<<bns?1024:2048,256,0,stream>>>(partB, Y, Cout, Yout, Cp, cf,
                                                    16384*256, 4, bns, 256);
  };
  // tconv per parity class split S=2 -> z = cls*2+kz, 1024 blocks
  auto l2_tconv = [&](const unsigned short* y){
    LA_yg al{y, zp16, 3,3,8, 0,0};
    EpiM ep{}; ep.C=partB; ep.S_MN=16384*128; ep.Kc=512; ep.lgS=1; ep.zp=zp16;
    mgemm_k<LA_yg,EPI_TPART><<<dim3(1,128,8),512,0,stream>>>(al, wcls2, 16384,128,1024, ep);
    tcomb_k<<<2048,256,0,stream>>>(partB, h1, rH, 4,4,7, 2, 16384*128, 1048576);
  };
  l2_fwd(h1, nullptr, nullptr, cA, nullptr, 0.f, nullptr);
  l2_tconv(cA);
  l2_fwd(rH, cA, cA, cB, yA, coef[2], nullptr);
  l2_tconv(yA);
  l2_fwd(rH, yA, cB, cA, yB, coef[3], nullptr);
  l2_tconv(yB);
  hipMemsetAsync(bnsum, 0, 2*256*sizeof(float), stream);
  l2_fwd(rH, yB, nullptr, cB, nullptr, 0.f, bnsum);    // pre-BN + fused stats
  bn_apply_k<<<2048,256,0,stream>>>(cB, bnsum, g2, b2, h2, 16384, 256, 1.f/16384.f);

  // ---------- Layer 3: (4096,512), K=4096: split-K S=8 -> 1024 blocks ----------
  auto l3_fwd = [&](const unsigned short* src, const unsigned short* Y, const unsigned short* Cp,
                    unsigned short* Cout, unsigned short* Yout, float cf, float* bns){
    LA_nhwc al{src, zp16, 3,3,8};
    EpiM ep{}; ep.C=partB; ep.S_MN=4096*512; ep.Kc=512; ep.zp=zp16;
    mgemm_k<LA_nhwc,EPI_PARTIAL><<<dim3(4,32,8),512,0,stream>>>(al, wT3, 4096,512,4096, ep);
    splitk_shrink_k<<<1024,256,0,stream>>>(partB, Y, Cout, Yout, Cp, cf,
                                           4096*512, 8, bns, 512);
  };
  // tconv per class split S=4 -> z = cls*4+kz, 1024 blocks
  auto l3_tconv = [&](const unsigned short* y){
    LA_yg al{y, zp16, 2,2,9, 0,0};
    EpiM ep{}; ep.C=partB; ep.S_MN=4096*256; ep.Kc=512; ep.lgS=2; ep.zp=zp16;
    mgemm_k<LA_yg,EPI_TPART><<<dim3(2,32,16),512,0,stream>>>(al, wcls3, 4096,256,2048, ep);
    tcomb_k<<<2048,256,0,stream>>>(partB, h2, rH, 3,3,8, 4, 4096*256, 524288);
  };
  l3_fwd(h2, nullptr, nullptr, cA, nullptr, 0.f, nullptr);
  l3_tconv(cA);
  l3_fwd(rH, cA, cA, cB, yA, coef[2], nullptr);
  l3_tconv(yA);
  l3_fwd(rH, yA, cB, cA, yB, coef[3], nullptr);
  l3_tconv(yB);
  hipMemsetAsync(bnsum, 0, 2*512*sizeof(float), stream);
  l3_fwd(rH, yB, nullptr, cB, nullptr, 0.f, bnsum);    // pre-BN + fused stats
  bn_apply_k<<<2048,256,0,stream>>>(cB, bnsum, g3, b3, h3, 4096, 512, 1.f/4096.f);

  // ---------- Layer 4 (Gram form, exact): flat (256,8192) -> (256,256) ----------
  // r = x - yW ; c = shrink(y + ss*r*W^T) == shrink(y + b - ss*(y*G)),
  // b = ss*x*W^T (once), G = W*W^T (once). No boundary terms (single output pos).
  { // b and c0 = shrink(b)
    LA_ident al{h3, 8192};
    EpiM ep{}; ep.C=partB; ep.S_MN=65536; ep.Kc=256; ep.zp=zp16;
    mgemm_k<LA_ident,EPI_PARTIAL><<<dim3(2,2,32),512,0,stream>>>(al, wT4, 256,256,8192, ep);
    combine_k<<<32,256,0,stream>>>(partB, bb, cA, 65536, 32, 1);   // bb = ss*sum, cA = c0
  }
  { // G = Wn4 * Wn4^T
    LA_ident al{wT4, 8192};
    EpiM ep{}; ep.C=partB; ep.S_MN=65536; ep.Kc=256; ep.zp=zp16;
    mgemm_k<LA_ident,EPI_PARTIAL><<<dim3(2,2,32),512,0,stream>>>(al, wT4, 256,256,8192, ep);
    combine_k<<<32,256,0,stream>>>(partB, Gm, nullptr, 65536, 32, 0);
  }
  auto l4_gram = [&](const unsigned short* Y, const unsigned short* Cp,
                     unsigned short* Cout, unsigned short* Yout, float cf){
    LA_ident al{Y, 256};
    EpiM ep{}; ep.C=Cout; ep.Y=Y; ep.Cprev=Cp; ep.Yout=Yout; ep.coef=cf;
    ep.img=bb; ep.zp=zp16;
    mgemm_k<LA_ident,EPI_GRAM><<<dim3(2,2,1),512,0,stream>>>(al, Gm, 256,256,256, ep);
  };
  l4_gram(cA, cA, cB, yA, coef[2]);        // c1, y2  (y1 = c0 = cA)
  l4_gram(yA, cB, cA, yB, coef[3]);        // c2, y3
  l4_gram(yB, nullptr, cB, nullptr, 0.f);  // c3

  norm_rows_k<<<256,256,0,stream>>>(cB, out);
}

// Round 15
// 823.560 us; speedup vs baseline: 1.0492x; 1.0492x over previous
//
#include <hip/hip_runtime.h>
#include <math.h>

#define SS   0.1f
#define THRC 0.01f   // LMBD * MU

typedef __attribute__((ext_vector_type(8))) short s16x8;
typedef __attribute__((ext_vector_type(4))) float f32x4;

__device__ __forceinline__ float b2f(unsigned short u){
  union{unsigned int i; float f;} v; v.i = ((unsigned int)u)<<16; return v.f;
}
__device__ __forceinline__ unsigned short f2b(float f){
  union{float f; unsigned int i;} v; v.f = f;
  return (unsigned short)((v.i + 0x7fffu + ((v.i>>16)&1u))>>16);  // RNE
}
__device__ __forceinline__ s16x8 as_s16x8(uint4 u){
  union{uint4 a; s16x8 b;} c; c.a = u; return c.b;
}
// 8 quads/row; XOR swizzle -> <=2-way conflicts on ds_read. DMA writes LDS linearly
// with SOURCE quads pre-swizzled (same involution both sides).
__device__ __forceinline__ int swz8(int row, int q){ return (row<<3) | (q ^ (row&7)); }

// async global->LDS, 16B/lane; dest = wave-uniform base + lane*16, source per-lane.
__device__ __forceinline__ void gld16(const void* g, void* l){
  __builtin_amdgcn_global_load_lds(
      (const __attribute__((address_space(1))) unsigned int*)g,
      (__attribute__((address_space(3))) unsigned int*)l, 16, 0, 0);
}

enum { EPI_FIRST=0, EPI_UPDATE=1, EPI_PARTIAL=2, EPI_TPART=3, EPI_GRAM=4 };

struct EpiM {
  unsigned short* C;            // dest (c / partial)
  const unsigned short* Y;      // y for UPDATE/GRAM
  const unsigned short* Cprev;  // c_{t-1} for fused y-update
  unsigned short* Yout;         // fused y_{t+1} output (optional)
  const unsigned short* img;    // b = ss*conv(x) for GRAM
  const unsigned short* zp;     // 16B zeros page for OOB DMA lanes
  float coef;
  int S_MN, Kc, lgS;            // split-K geometry
};

// -------- A-tile loaders: return 16B-aligned address of 8 contiguous bf16 --------
struct LA_ident {
  const unsigned short* A; int K;
  __device__ void setz(int){}
  __device__ __forceinline__ const unsigned short* addr(int m, int k8) const {
    return A + (size_t)m*K + ((size_t)k8<<3);
  }
};
struct LA_nhwc {   // im2col, NHWC bf16, stride2 pad1 k4; k = (kh*4+kw)*C + i
  const unsigned short* img; const unsigned short* zp; int lH, lW, lC;
  __device__ void setz(int){}
  __device__ __forceinline__ const unsigned short* addr(int m, int k8) const {
    int lWo = lW-1, lHo = lH-1;
    int wo = m & ((1<<lWo)-1); int t = m>>lWo; int ho = t & ((1<<lHo)-1); int b = t>>lHo;
    int k = k8<<3; int kk = k>>lC; int i = k & ((1<<lC)-1);
    int kw = kk&3, kh = kk>>2;
    int h = 2*ho + kh - 1, w = 2*wo + kw - 1;
    if ((unsigned)h >= (1u<<lH) || (unsigned)w >= (1u<<lW)) return zp;
    return img + (((((((size_t)b<<lH)|h)<<lW)|w))<<lC) + i;
  }
};
struct LA_yg {     // parity-class tconv gather of code y; k = (th*2+tw)*O + o
  const unsigned short* y; const unsigned short* zp; int lHo, lWo, lO, ph, pw;
  __device__ void setz(int z){ ph = z>>1; pw = z&1; }
  __device__ __forceinline__ const unsigned short* addr(int m, int k8) const {
    int l = m & ((1<<lWo)-1); int t = m>>lWo; int j = t & ((1<<lHo)-1); int b = t>>lHo;
    int k = k8<<3; int tt = k>>lO; int o = k & ((1<<lO)-1);
    int th = tt>>1, tw = tt&1;
    int ho = ph ? (j+1-th) : (j-th);
    int wo = pw ? (l+1-tw) : (l-tw);
    if ((unsigned)ho >= (1u<<lHo) || (unsigned)wo >= (1u<<lWo)) return zp;
    return y + (((((((size_t)b<<lHo)|ho)<<lWo)|wo))<<lO) + o;
  }
};
struct LA_padb {   // layer-1 im2col from padded bf16 NHWC4 [256][34][34][4]; k=(kh*4+kw)*4+c
  const unsigned short* img;
  __device__ void setz(int){}
  __device__ __forceinline__ const unsigned short* addr(int m, int k8) const {
    int wo = m&15, t = m>>4, ho = t&15, b = t>>4;
    int kh = k8>>1, kw0 = (k8&1)<<1;
    int h = 2*ho + kh, w = 2*wo + kw0;          // w even -> 16B aligned
    return img + (((size_t)b*34 + h)*34 + w)*4;
  }
};

// ---- MFMA GEMM: 128x128 tile, BK=64, 8 waves (2x4), wave=64x32, SINGLE-buffer ----
// m97 design point: 32KB LDS -> 4 blocks/CU co-resident (512thr x 4 = 2048 = CU cap).
// Inter-block wave overlap hides the per-step drain. Host splits K so hot dispatches
// have ~1024 blocks. Split-K reduction stays in SEPARATE kernels: the fused
// last-block variant (R10/R11) required per-block device-scope fences -> L2
// writeback/invalidate storms (MfmaUtil 1.5%). Kernel-boundary fence is once, not 1024x.
template<class AL, int EPI>
__global__ __launch_bounds__(512)
void mgemm_k(AL al, const unsigned short* __restrict__ Bw, int M, int N, int K, EpiM ep)
{
  __shared__ uint4 As[1024];   // 16KB
  __shared__ uint4 Bs[1024];   // 16KB
  const int tid = threadIdx.x;
  const int bm = blockIdx.y<<7, bn = blockIdx.x<<7;
  const int z = blockIdx.z;
  int kb = 0, ke = K;
  const unsigned short* Bp = Bw;
  if (EPI == EPI_PARTIAL){ kb = z*ep.Kc; ke = kb + ep.Kc; }
  if (EPI == EPI_TPART){
    int cls = z >> ep.lgS, kz = z & ((1<<ep.lgS)-1);
    Bp = Bw + (size_t)cls*(size_t)N*K; al.setz(cls);
    kb = kz*ep.Kc; ke = kb + ep.Kc;
  }

  f32x4 acc[4][2];
  #pragma unroll
  for (int i=0;i<4;++i)
    #pragma unroll
    for (int j=0;j<2;++j){ acc[i][j][0]=0.f; acc[i][j][1]=0.f; acc[i][j][2]=0.f; acc[i][j][3]=0.f; }

  const int lane = tid & 63, wid = tid >> 6;
  const int wm = (wid>>2)<<6, wn = (wid&3)<<5;     // wave tile 64x32
  const int fr = lane & 15, fq = lane >> 4;

  // DMA slot mapping: slot s -> row s>>3; lds-quad j=s&7 holds global quad
  // q = j ^ (row&7) (self-inverse; matches swz8 on the read side).
  auto issueA = [&](int k0){
    int k8 = k0>>3;
    #pragma unroll
    for (int i=0;i<2;++i){
      int s  = (wid<<7) + (i<<6) + lane;
      int sr = s>>3, q = (s&7) ^ (sr&7);
      gld16(al.addr(bm+sr, k8+q), (void*)&As[(wid<<7) + (i<<6)]);
    }
  };
  auto issueB = [&](int k0){
    int k8 = k0>>3;
    #pragma unroll
    for (int i=0;i<2;++i){
      int s  = (wid<<7) + (i<<6) + lane;
      int sr = s>>3, q = (s&7) ^ (sr&7);
      int gn = bn + sr;
      const unsigned short* src = (gn < N) ? Bp + (size_t)gn*K + ((size_t)(k8+q)<<3) : ep.zp;
      gld16(src, (void*)&Bs[(wid<<7) + (i<<6)]);
    }
  };

  for (int k0 = kb; k0 < ke; k0 += 64){
    issueA(k0); issueB(k0);
    asm volatile("s_waitcnt vmcnt(0)" ::: "memory");  // my DMAs landed
    __builtin_amdgcn_s_barrier();                     // everyone's landed
    __builtin_amdgcn_sched_barrier(0);
    #pragma unroll
    for (int half=0; half<2; ++half){
      const int qb = (half<<2) | fq;
      s16x8 af[4], bf[2];
      #pragma unroll
      for (int mi=0;mi<4;++mi) af[mi] = as_s16x8(As[swz8(wm + mi*16 + fr, qb)]);
      #pragma unroll
      for (int ni=0;ni<2;++ni) bf[ni] = as_s16x8(Bs[swz8(wn + ni*16 + fr, qb)]);
      #pragma unroll
      for (int mi=0;mi<4;++mi)
        #pragma unroll
        for (int ni=0;ni<2;++ni)
          acc[mi][ni] = __builtin_amdgcn_mfma_f32_16x16x32_bf16(af[mi], bf[ni], acc[mi][ni], 0,0,0);
    }
    if (k0 + 64 < ke){
      __builtin_amdgcn_s_barrier();                   // reads retired -> safe overwrite
      __builtin_amdgcn_sched_barrier(0);
    }
  }

  // epilogue: D lane map col=lane&15, row=(lane>>4)*4+reg
  #pragma unroll
  for (int mi=0;mi<4;++mi){
    #pragma unroll
    for (int ni=0;ni<2;++ni){
      int n = bn + wn + ni*16 + fr;
      if (n >= N) continue;
      int mb = bm + wm + mi*16 + (fq<<2);
      #pragma unroll
      for (int r=0;r<4;++r){
        int m = mb + r;
        float a = acc[mi][ni][r];
        if (EPI == EPI_FIRST){
          float v = SS*a - THRC; v = v>0.f ? v : 0.f;
          ep.C[(size_t)m*N + n] = f2b(v);
        } else if (EPI == EPI_UPDATE){
          size_t idx = (size_t)m*N + n;
          float v = b2f(ep.Y[idx]) + SS*a - THRC; v = v>0.f ? v : 0.f;
          ep.C[idx] = f2b(v);
          if (ep.Yout) ep.Yout[idx] = f2b(v + ep.coef*(v - b2f(ep.Cprev[idx])));
        } else if (EPI == EPI_PARTIAL || EPI == EPI_TPART){
          ep.C[(size_t)z*ep.S_MN + (size_t)m*N + n] = f2b(a);
        } else { // EPI_GRAM: c = shrink(y + b - ss*(y*G)), fused y-update
          size_t idx = (size_t)m*N + n;
          float v = b2f(ep.Y[idx]) + b2f(ep.img[idx]) - SS*a - THRC; v = v>0.f ? v : 0.f;
          ep.C[idx] = f2b(v);
          if (ep.Yout) ep.Yout[idx] = f2b(v + ep.coef*(v - b2f(ep.Cprev[idx])));
        }
      }
    }
  }
}

// ---------------- weight normalization ----------------
__global__ __launch_bounds__(64)
void wnorm1_k(const float* __restrict__ w, unsigned short* __restrict__ wf1,
              unsigned short* __restrict__ wcolT)
{
  int o = blockIdx.x, tid = threadIdx.x;
  __shared__ float red[64];
  float v = (tid < 48) ? w[(size_t)o*48 + tid] : 0.f;  // tid = c*16 + t
  red[tid] = v*v; __syncthreads();
  for (int d=32; d>0; d>>=1){ if (tid<d) red[tid] += red[tid+d]; __syncthreads(); }
  float nv = v * rsqrtf(red[0]);
  if (tid < 48){
    int c = tid>>4, t = tid&15;
    wf1[(size_t)o*64 + t*4 + c] = f2b(nv);
    wcolT[(size_t)(t*4+c)*128 + o] = f2b(nv);
  } else {
    int t = tid - 48;
    wf1[(size_t)o*64 + t*4 + 3] = 0;
    wcolT[(size_t)(t*4+3)*128 + o] = 0;
  }
}
__global__ __launch_bounds__(256)
void wnormX_k(const float* __restrict__ w, int Cin, int O,
              unsigned short* __restrict__ wT, unsigned short* __restrict__ wclsT,
              unsigned short* __restrict__ wEO)
{
  int o = blockIdx.x, tid = threadIdx.x; int E = Cin*16;
  __shared__ float red[256];
  float s = 0.f;
  for (int e = tid; e < E; e += 256){ float v = w[(size_t)o*E + e]; s += v*v; }
  red[tid] = s; __syncthreads();
  for (int d=128; d>0; d>>=1){ if (tid<d) red[tid] += red[tid+d]; __syncthreads(); }
  float scale = rsqrtf(red[0]);
  for (int e = tid; e < E; e += 256){
    float v = w[(size_t)o*E + e] * scale;
    int i = e>>4, t = e&15, kh = t>>2, kw = t&3;
    int ee = t*Cin + i;
    if (wT)  wT[(size_t)o*E + ee] = f2b(v);
    if (wEO) wEO[(size_t)ee*O + o] = f2b(v);
    if (wclsT){
      int ph = (kh&1)^1, pw = (kw&1)^1, cls = ph*2+pw;
      int tt = (kh>>1)*2 + (kw>>1);
      wclsT[(((size_t)cls*Cin + i)*4 + tt)*O + o] = f2b(v);
    }
  }
}

// ---------------- small kernels ----------------
// split-K reduce + shrink (+ fused y-update), vectorized x8
__global__ void splitk_shrink_k(const unsigned short* __restrict__ part,
                                const unsigned short* __restrict__ Y,
                                unsigned short* __restrict__ C,
                                unsigned short* __restrict__ Yout,
                                const unsigned short* __restrict__ Cprev,
                                float coef, int MN, int S)
{
  int total8 = MN>>3;
  for (int i8 = blockIdx.x*blockDim.x + threadIdx.x; i8 < total8; i8 += gridDim.x*blockDim.x){
    size_t off = (size_t)i8<<3;
    float s[8];
    #pragma unroll
    for (int j=0;j<8;++j) s[j]=0.f;
    for (int zz = 0; zz < S; ++zz){
      uint4 pv = *(const uint4*)(part + (size_t)zz*MN + off);
      const unsigned short* pe = (const unsigned short*)&pv;
      #pragma unroll
      for (int j=0;j<8;++j) s[j] += b2f(pe[j]);
    }
    uint4 yv = make_uint4(0,0,0,0), cp = make_uint4(0,0,0,0);
    if (Y)    yv = *(const uint4*)(Y + off);
    if (Yout) cp = *(const uint4*)(Cprev + off);
    const unsigned short* ye = (const unsigned short*)&yv;
    const unsigned short* ce = (const unsigned short*)&cp;
    unsigned short co[8], yo[8];
    #pragma unroll
    for (int j=0;j<8;++j){
      float v = (Y ? b2f(ye[j]) : 0.f) + SS*s[j] - THRC; v = v>0.f ? v : 0.f;
      co[j] = f2b(v);
      if (Yout) yo[j] = f2b(v + coef*(v - b2f(ce[j])));
    }
    *(uint4*)(C + off) = *(const uint4*)co;
    if (Yout) *(uint4*)(Yout + off) = *(const uint4*)yo;
  }
}

// split-K combine: mode 0 -> out1 = f2b(sum); mode 1 -> out1 = f2b(SS*sum),
// out2 = f2b(relu(SS*sum - THRC))   (L4: b and c0 in one pass)
__global__ void combine_k(const unsigned short* __restrict__ part,
                          unsigned short* __restrict__ out1,
                          unsigned short* __restrict__ out2,
                          int MN, int S, int mode)
{
  int total8 = MN>>3;
  for (int i8 = blockIdx.x*blockDim.x + threadIdx.x; i8 < total8; i8 += gridDim.x*blockDim.x){
    size_t off = (size_t)i8<<3;
    float s[8];
    #pragma unroll
    for (int j=0;j<8;++j) s[j]=0.f;
    for (int zz = 0; zz < S; ++zz){
      uint4 pv = *(const uint4*)(part + (size_t)zz*MN + off);
      const unsigned short* pe = (const unsigned short*)&pv;
      #pragma unroll
      for (int j=0;j<8;++j) s[j] += b2f(pe[j]);
    }
    unsigned short o1[8], o2[8];
    #pragma unroll
    for (int j=0;j<8;++j){
      if (mode == 0){ o1[j] = f2b(s[j]); }
      else {
        float bsc = SS*s[j];
        o1[j] = f2b(bsc);
        float v = bsc - THRC; v = v>0.f ? v : 0.f;
        o2[j] = f2b(v);
      }
    }
    *(uint4*)(out1 + off) = *(const uint4*)o1;
    if (mode == 1) *(uint4*)(out2 + off) = *(const uint4*)o2;
  }
}

// tconv split-K combine: r = img - sum_kz partial[cls(idx)*S+kz], vectorized x8 over c
__global__ void tcomb_k(const unsigned short* __restrict__ part,
                        const unsigned short* __restrict__ img,
                        unsigned short* __restrict__ outp,
                        int lH, int lW, int lC, int S, int MN, int total8)
{
  for (int i8 = blockIdx.x*blockDim.x + threadIdx.x; i8 < total8; i8 += gridDim.x*blockDim.x){
    size_t idx = (size_t)i8<<3;
    int c = (int)(idx & ((1u<<lC)-1));
    int w = (int)(idx>>lC) & ((1<<lW)-1);
    int h = (int)(idx>>(lC+lW)) & ((1<<lH)-1);
    int b = (int)(idx>>(lC+lW+lH));
    int j = h>>1, l = w>>1, cls = ((h&1)<<1)|(w&1);
    int m = (((b<<(lH-1))|j)<<(lW-1))|l;
    int N = 1<<lC;
    const unsigned short* pb = part + ((size_t)cls*S)*MN + (size_t)m*N + c;
    float s[8];
    #pragma unroll
    for (int q=0;q<8;++q) s[q]=0.f;
    for (int kz=0; kz<S; ++kz){
      uint4 pv = *(const uint4*)(pb + (size_t)kz*MN);
      const unsigned short* pe = (const unsigned short*)&pv;
      #pragma unroll
      for (int q=0;q<8;++q) s[q] += b2f(pe[q]);
    }
    uint4 iv = *(const uint4*)(img + idx);
    const unsigned short* ie = (const unsigned short*)&iv;
    unsigned short ro[8];
    #pragma unroll
    for (int q=0;q<8;++q) ro[q] = f2b(b2f(ie[q]) - s[q]);
    *(uint4*)(outp + idx) = *(const uint4*)ro;
  }
}

__global__ void pad_x_k(const float* __restrict__ x, unsigned short* __restrict__ xpb){
  int idx = blockIdx.x*256 + threadIdx.x;
  if (idx >= 262144) return;
  int w = idx&31, t = idx>>5, h = t&31, b = t>>5;
  size_t src = (size_t)b*3072 + h*32 + w;
  unsigned short* d = xpb + (((size_t)b*34 + h+1)*34 + w+1)*4;
  d[0] = f2b(x[src]); d[1] = f2b(x[src+1024]); d[2] = f2b(x[src+2048]); d[3] = 0;
}

__global__ void l1_resid_k(const unsigned short* __restrict__ Col,
                           const float* __restrict__ x, unsigned short* __restrict__ r1pb)
{
  int idx = blockIdx.x*256 + threadIdx.x;
  if (idx >= 262144) return;
  int w = idx&31, t = idx>>5, h = t&31, b = t>>5;
  float a0=0.f, a1=0.f, a2=0.f;
  #pragma unroll
  for (int kh=0; kh<4; ++kh){
    int hh = h+1-kh; if (hh & 1) continue; int ho = hh>>1; if ((unsigned)ho >= 16u) continue;
    #pragma unroll
    for (int kw=0; kw<4; ++kw){
      int ww = w+1-kw; if (ww & 1) continue; int wo = ww>>1; if ((unsigned)wo >= 16u) continue;
      int m = (b*16+ho)*16+wo;
      // 4 contiguous shorts (8B aligned): channels 0..2 + zero pad channel
      uint2 pv = *(const uint2*)(Col + (size_t)m*64 + (kh*4+kw)*4);
      const unsigned short* pe = (const unsigned short*)&pv;
      a0 += b2f(pe[0]); a1 += b2f(pe[1]); a2 += b2f(pe[2]);
    }
  }
  size_t src = (size_t)b*3072 + h*32 + w;
  unsigned short* d = r1pb + (((size_t)b*34 + h+1)*34 + w+1)*4;
  d[0] = f2b(x[src] - a0); d[1] = f2b(x[src+1024] - a1); d[2] = f2b(x[src+2048] - a2); d[3] = 0;
}

__global__ void bn_stats_k(const unsigned short* __restrict__ d, float* __restrict__ sums,
                           int rows, int O){
  for (int c = threadIdx.x; c < O; c += blockDim.x){
    float a = 0.f, b = 0.f;
    for (int r = blockIdx.x; r < rows; r += gridDim.x){
      float v = b2f(d[(size_t)r*O + c]); a += v; b += v*v;
    }
    atomicAdd(&sums[c], a); atomicAdd(&sums[O+c], b);
  }
}
__global__ void bn_apply_k(const unsigned short* __restrict__ d, const float* __restrict__ sums,
                           const float* __restrict__ g, const float* __restrict__ bta,
                           unsigned short* __restrict__ outp, int rows, int O, float inv_cnt){
  int total = rows*O;
  for (int i = blockIdx.x*blockDim.x + threadIdx.x; i < total; i += gridDim.x*blockDim.x){
    int c = i % O;
    float mean = sums[c]*inv_cnt;
    float var  = sums[O+c]*inv_cnt - mean*mean;
    float v = g[c]*(b2f(d[i])-mean)*rsqrtf(var + 1e-5f) + bta[c];
    outp[i] = f2b(v >= 0.f ? v : 0.2f*v);
  }
}

__global__ __launch_bounds__(256)
void norm_rows_k(const unsigned short* __restrict__ h, float* __restrict__ out){
  int row = blockIdx.x, tid = threadIdx.x;
  __shared__ float red[256];
  float v = b2f(h[(size_t)row*256 + tid]);
  red[tid] = v*v; __syncthreads();
  for (int d=128; d>0; d>>=1){ if (tid<d) red[tid] += red[tid+d]; __syncthreads(); }
  float nrm = sqrtf(red[0]); nrm = nrm > 1e-12f ? nrm : 1e-12f;
  out[(size_t)row*256 + tid] = v / nrm;
}

// ---------------- host ----------------
extern "C" void kernel_launch(void* const* d_in, const int* in_sizes, int n_in,
                              void* d_out, int out_size, void* d_ws, size_t ws_size,
                              hipStream_t stream)
{
  const float* x  = (const float*)d_in[0];
  const float* w1 = (const float*)d_in[1];
  const float* w2 = (const float*)d_in[2];
  const float* w3 = (const float*)d_in[3];
  const float* w4 = (const float*)d_in[4];
  const float* g2 = (const float*)d_in[5];
  const float* b2 = (const float*)d_in[6];
  const float* g3 = (const float*)d_in[7];
  const float* b3 = (const float*)d_in[8];
  float* out = (float*)d_out;

  char* p = (char*)d_ws;
  auto ah = [&](size_t n){ unsigned short* r = (unsigned short*)p; p += n*2; return r; };
  auto af = [&](size_t n){ float* r = (float*)p; p += n*4; return r; };

  unsigned short* wf1    = ah(128*64);
  unsigned short* wcol1T = ah(64*128);
  unsigned short* wT2    = ah((size_t)256*2048);
  unsigned short* wcls2  = ah((size_t)4*128*1024);
  unsigned short* wT3    = ah((size_t)512*4096);
  unsigned short* wcls3  = ah((size_t)4*256*2048);
  unsigned short* wT4    = ah((size_t)256*8192);
  unsigned short* Gm     = ah((size_t)256*256);   // L4 Gram W*W^T (bf16)
  unsigned short* bb     = ah((size_t)65536);     // L4 b = ss*conv(h3)
  unsigned short* h1     = ah((size_t)8388608);
  unsigned short* h2     = ah((size_t)4194304);
  unsigned short* h3     = ah((size_t)2097152);
  unsigned short* cA     = ah((size_t)8388608);
  unsigned short* cB     = ah((size_t)8388608);
  unsigned short* yA     = ah((size_t)8388608);
  unsigned short* yB     = ah((size_t)8388608);
  unsigned short* rH     = ah((size_t)8388608);
  // union scratch (33.5MB): L1 {Col 8.39 + xpb 2.37 + r1pb 2.37}
  //                         L2/L3 splits {8x/16x partial slices} / L4 {4.2MB}
  char* regionA = p; p += 33554432;
  unsigned short* Col    = (unsigned short*)regionA;                       // 65536 x 64 bf16
  unsigned short* xpb    = (unsigned short*)(regionA + 8388608);           // 256*34*34*4 bf16
  unsigned short* r1pb   = (unsigned short*)(regionA + 8388608 + 2367488);
  unsigned short* partB  = (unsigned short*)regionA;                       // split-K partials
  float* bnsum = af(1024);
  unsigned short* zp16 = ah(128);   // zeros page for OOB DMA lanes (256B)

  double tk = 1.0; float coef[4] = {0.f,0.f,0.f,0.f};
  for (int t = 1; t < 4; ++t){
    double tkp = tk; tk = (1.0 + sqrt(1.0 + 4.0*tkp*tkp))*0.5;
    coef[t] = (float)((tkp - 1.0)/tk);
  }

  hipMemsetAsync(zp16, 0, 256, stream);
  hipMemsetAsync(xpb,  0, 2367488, stream);
  hipMemsetAsync(r1pb, 0, 2367488, stream);
  pad_x_k<<<1024,256,0,stream>>>(x, xpb);
  wnorm1_k<<<128, 64, 0, stream>>>(w1, wf1, wcol1T);
  wnormX_k<<<256,256,0,stream>>>(w2, 128, 256, wT2, wcls2, nullptr);
  wnormX_k<<<512,256,0,stream>>>(w3, 256, 512, wT3, wcls3, nullptr);
  wnormX_k<<<256,256,0,stream>>>(w4, 512, 256, wT4, nullptr, nullptr);

  // ---------- Layer 1: padded bf16 NHWC4 -> code (65536,128), K=64 ----------
  auto l1_fwd = [&](const unsigned short* src, const unsigned short* Y, const unsigned short* Cp,
                    unsigned short* Cout, unsigned short* Yout, float cf){
    LA_padb al{src};
    EpiM ep{}; ep.C=Cout; ep.Y=Y; ep.Cprev=Cp; ep.Yout=Yout; ep.coef=cf; ep.zp=zp16;
    dim3 g(1, 512, 1);
    if (Y) mgemm_k<LA_padb,EPI_UPDATE><<<g,512,0,stream>>>(al, wf1, 65536,128,64, ep);
    else   mgemm_k<LA_padb,EPI_FIRST ><<<g,512,0,stream>>>(al, wf1, 65536,128,64, ep);
  };
  auto l1_tconv = [&](const unsigned short* y){
    LA_ident al{y, 128};
    EpiM ep{}; ep.C=Col; ep.S_MN=0; ep.Kc=128; ep.zp=zp16;
    mgemm_k<LA_ident,EPI_PARTIAL><<<dim3(1,512,1),512,0,stream>>>(al, wcol1T, 65536,64,128, ep);
    l1_resid_k<<<1024,256,0,stream>>>(Col, x, r1pb);
  };
  l1_fwd(xpb,  nullptr, nullptr, cA, nullptr, 0.f);    // c0 (=y1)
  l1_tconv(cA);
  l1_fwd(r1pb, cA, cA, cB, yA, coef[2]);               // c1, y2
  l1_tconv(yA);
  l1_fwd(r1pb, yA, cB, cA, yB, coef[3]);               // c2, y3
  l1_tconv(yB);
  l1_fwd(r1pb, yB, nullptr, h1, nullptr, 0.f);         // c3 -> h1

  // ---------- Layer 2: (16384,256), K=2048: split-K S=4 -> 1024 blocks ----------
  auto l2_fwd = [&](const unsigned short* src, const unsigned short* Y, const unsigned short* Cp,
                    unsigned short* Cout, unsigned short* Yout, float cf){
    LA_nhwc al{src, zp16, 4,4,7};
    EpiM ep{}; ep.C=partB; ep.S_MN=16384*256; ep.Kc=512; ep.zp=zp16;
    mgemm_k<LA_nhwc,EPI_PARTIAL><<<dim3(2,128,4),512,0,stream>>>(al, wT2, 16384,256,2048, ep);
    splitk_shrink_k<<<2048,256,0,stream>>>(partB, Y, Cout, Yout, Cp, cf, 16384*256, 4);
  };
  // tconv per parity class split S=2 -> z = cls*2+kz, 1024 blocks
  auto l2_tconv = [&](const unsigned short* y){
    LA_yg al{y, zp16, 3,3,8, 0,0};
    EpiM ep{}; ep.C=partB; ep.S_MN=16384*128; ep.Kc=512; ep.lgS=1; ep.zp=zp16;
    mgemm_k<LA_yg,EPI_TPART><<<dim3(1,128,8),512,0,stream>>>(al, wcls2, 16384,128,1024, ep);
    tcomb_k<<<2048,256,0,stream>>>(partB, h1, rH, 4,4,7, 2, 16384*128, 1048576);
  };
  l2_fwd(h1, nullptr, nullptr, cA, nullptr, 0.f);
  l2_tconv(cA);
  l2_fwd(rH, cA, cA, cB, yA, coef[2]);
  l2_tconv(yA);
  l2_fwd(rH, yA, cB, cA, yB, coef[3]);
  l2_tconv(yB);
  l2_fwd(rH, yB, nullptr, cB, nullptr, 0.f);           // pre-BN
  hipMemsetAsync(bnsum, 0, 2*256*sizeof(float), stream);
  bn_stats_k<<<256,256,0,stream>>>(cB, bnsum, 16384, 256);
  bn_apply_k<<<2048,256,0,stream>>>(cB, bnsum, g2, b2, h2, 16384, 256, 1.f/16384.f);

  // ---------- Layer 3: (4096,512), K=4096: split-K S=8 -> 1024 blocks ----------
  auto l3_fwd = [&](const unsigned short* src, const unsigned short* Y, const unsigned short* Cp,
                    unsigned short* Cout, unsigned short* Yout, float cf){
    LA_nhwc al{src, zp16, 3,3,8};
    EpiM ep{}; ep.C=partB; ep.S_MN=4096*512; ep.Kc=512; ep.zp=zp16;
    mgemm_k<LA_nhwc,EPI_PARTIAL><<<dim3(4,32,8),512,0,stream>>>(al, wT3, 4096,512,4096, ep);
    splitk_shrink_k<<<1024,256,0,stream>>>(partB, Y, Cout, Yout, Cp, cf, 4096*512, 8);
  };
  // tconv per class split S=4 -> z = cls*4+kz, 1024 blocks
  auto l3_tconv = [&](const unsigned short* y){
    LA_yg al{y, zp16, 2,2,9, 0,0};
    EpiM ep{}; ep.C=partB; ep.S_MN=4096*256; ep.Kc=512; ep.lgS=2; ep.zp=zp16;
    mgemm_k<LA_yg,EPI_TPART><<<dim3(2,32,16),512,0,stream>>>(al, wcls3, 4096,256,2048, ep);
    tcomb_k<<<2048,256,0,stream>>>(partB, h2, rH, 3,3,8, 4, 4096*256, 524288);
  };
  l3_fwd(h2, nullptr, nullptr, cA, nullptr, 0.f);
  l3_tconv(cA);
  l3_fwd(rH, cA, cA, cB, yA, coef[2]);
  l3_tconv(yA);
  l3_fwd(rH, yA, cB, cA, yB, coef[3]);
  l3_tconv(yB);
  l3_fwd(rH, yB, nullptr, cB, nullptr, 0.f);
  hipMemsetAsync(bnsum, 0, 2*512*sizeof(float), stream);
  bn_stats_k<<<256,256,0,stream>>>(cB, bnsum, 4096, 512);
  bn_apply_k<<<2048,256,0,stream>>>(cB, bnsum, g3, b3, h3, 4096, 512, 1.f/4096.f);

  // ---------- Layer 4 (Gram form, exact): flat (256,8192) -> (256,256) ----------
  // r = x - yW ; c = shrink(y + ss*r*W^T) == shrink(y + b - ss*(y*G)),
  // b = ss*x*W^T (once), G = W*W^T (once). No boundary terms (single output pos).
  { // b and c0 = shrink(b)
    LA_ident al{h3, 8192};
    EpiM ep{}; ep.C=partB; ep.S_MN=65536; ep.Kc=256; ep.zp=zp16;
    mgemm_k<LA_ident,EPI_PARTIAL><<<dim3(2,2,32),512,0,stream>>>(al, wT4, 256,256,8192, ep);
    combine_k<<<32,256,0,stream>>>(partB, bb, cA, 65536, 32, 1);   // bb = ss*sum, cA = c0
  }
  { // G = Wn4 * Wn4^T
    LA_ident al{wT4, 8192};
    EpiM ep{}; ep.C=partB; ep.S_MN=65536; ep.Kc=256; ep.zp=zp16;
    mgemm_k<LA_ident,EPI_PARTIAL><<<dim3(2,2,32),512,0,stream>>>(al, wT4, 256,256,8192, ep);
    combine_k<<<32,256,0,stream>>>(partB, Gm, nullptr, 65536, 32, 0);
  }
  auto l4_gram = [&](const unsigned short* Y, const unsigned short* Cp,
                     unsigned short* Cout, unsigned short* Yout, float cf){
    LA_ident al{Y, 256};
    EpiM ep{}; ep.C=Cout; ep.Y=Y; ep.Cprev=Cp; ep.Yout=Yout; ep.coef=cf;
    ep.img=bb; ep.zp=zp16;
    mgemm_k<LA_ident,EPI_GRAM><<<dim3(2,2,1),512,0,stream>>>(al, Gm, 256,256,256, ep);
  };
  l4_gram(cA, cA, cB, yA, coef[2]);        // c1, y2  (y1 = c0 = cA)
  l4_gram(yA, cB, cA, yB, coef[3]);        // c2, y3
  l4_gram(yB, nullptr, cB, nullptr, 0.f);  // c3

  norm_rows_k<<<256,256,0,stream>>>(cB, out);
}